// Round 12
// baseline (218.332 us; speedup 1.0000x reference)
//
#include <hip/hip_runtime.h>
#include <math.h>

typedef unsigned short u16;
typedef __bf16 bf16x8 __attribute__((ext_vector_type(8)));
typedef float f32x4 __attribute__((ext_vector_type(4)));

#define T_TOKENS 4096   // B*S
#define D_DIM    512
#define H_DIM    2048
#define E_NUM    8
#define CAP      4096   // per-expert worst-case capacity
#define NSLOT    (T_TOKENS * 2)
#define NCHUNK   16     // compaction chunks of 256 tokens

__device__ __forceinline__ u16 f2bf(float f) {
  unsigned int u = __builtin_bit_cast(unsigned int, f);
  u = (u + 0x7fffu + ((u >> 16) & 1u)) >> 16;   // RNE
  return (u16)u;
}

__device__ __forceinline__ void gload16(const void* g, void* l) {
  __builtin_amdgcn_global_load_lds(
      (__attribute__((address_space(1))) void*)(g),
      (__attribute__((address_space(3))) void*)(l), 16, 0, 0);
}

// gelu(v) ~= v * sigmoid(v*(1.59576912 + 0.071354817*v^2)); rcp instead of slow f32 div
__device__ __forceinline__ float gelu_fast(float v) {
  float u = v * __fmaf_rn(0.071354817f, v * v, 1.59576912f);
  float e = __expf(-u);
  return v * __builtin_amdgcn_rcpf(1.0f + e);
}

// ---------------- both weights: f32 [E][R][C] -> bf16 [E][C][R], one launch ----------------
__global__ __launch_bounds__(256) void transpose_both_kernel(const float* __restrict__ w1,
                                                             const float* __restrict__ w2,
                                                             u16* __restrict__ w1t,
                                                             u16* __restrict__ w2t) {
  __shared__ float tile[64][67];
  int bid = blockIdx.x;
  const float* in; u16* out; int R, C;
  if (bid < 2048) { in = w1; out = w1t; R = D_DIM; C = H_DIM; }
  else            { bid -= 2048; in = w2; out = w2t; R = H_DIM; C = D_DIM; }
  const int e = bid >> 8;
  const int t = bid & 255;
  const int nCx = C >> 6;
  const int c0 = (t % nCx) * 64, r0 = (t / nCx) * 64;
  const float* src = in + (size_t)e * D_DIM * H_DIM;
  u16* dst = out + (size_t)e * D_DIM * H_DIM;
  const int tid = threadIdx.x;
  {
    const int row = tid >> 2, cc = (tid & 3) * 16;
    const float* s = src + (size_t)(r0 + row) * C + c0 + cc;
#pragma unroll
    for (int j = 0; j < 4; j++)
      *(float4*)(&tile[row][cc + 4 * j]) = *(const float4*)(s + 4 * j);
  }
  __syncthreads();
  {
    const int c = tid >> 2, rc = (tid & 3) * 16;
    u16 buf[16];
#pragma unroll
    for (int j = 0; j < 16; j++) buf[j] = f2bf(tile[rc + j][c]);
    u16* d = dst + (size_t)(c0 + c) * R + r0 + rc;
    *(uint4*)(d)     = *(uint4*)(&buf[0]);
    *(uint4*)(d + 8) = *(uint4*)(&buf[8]);
  }
}

// ---------------- router + x->bf16 + zero(out) ----------------
__global__ __launch_bounds__(256) void router_kernel(const float* __restrict__ x,
                                                     const float* __restrict__ rw,
                                                     const float* __restrict__ rb,
                                                     int* __restrict__ topk_idx,
                                                     float* __restrict__ topk_p,
                                                     u16* __restrict__ xb,
                                                     float* __restrict__ outz) {
  {
    float4 z = {0.f, 0.f, 0.f, 0.f};
    float4* o = (float4*)(outz + (size_t)blockIdx.x * 2048);
    o[threadIdx.x] = z;
    o[threadIdx.x + 256] = z;
  }
  const int lane = threadIdx.x & 63;
  const int t = blockIdx.x * 4 + (threadIdx.x >> 6);
  const float* xr = x + (size_t)t * D_DIM + lane * 8;
  float xv[8];
  *(float4*)(&xv[0]) = *(const float4*)(xr);
  *(float4*)(&xv[4]) = *(const float4*)(xr + 4);
  ushort4 o0, o1;
  o0.x = f2bf(xv[0]); o0.y = f2bf(xv[1]); o0.z = f2bf(xv[2]); o0.w = f2bf(xv[3]);
  o1.x = f2bf(xv[4]); o1.y = f2bf(xv[5]); o1.z = f2bf(xv[6]); o1.w = f2bf(xv[7]);
  ushort4* xo = (ushort4*)(xb + (size_t)t * D_DIM + lane * 8);
  xo[0] = o0; xo[1] = o1;

  float acc[8] = {0.f,0.f,0.f,0.f,0.f,0.f,0.f,0.f};
#pragma unroll
  for (int j = 0; j < 8; j++) {
    const float4* w = (const float4*)(rw + (size_t)(lane * 8 + j) * E_NUM);
    float4 w0 = w[0], w1 = w[1];
    acc[0] += xv[j] * w0.x; acc[1] += xv[j] * w0.y;
    acc[2] += xv[j] * w0.z; acc[3] += xv[j] * w0.w;
    acc[4] += xv[j] * w1.x; acc[5] += xv[j] * w1.y;
    acc[6] += xv[j] * w1.z; acc[7] += xv[j] * w1.w;
  }
#pragma unroll
  for (int off = 32; off > 0; off >>= 1) {
#pragma unroll
    for (int e = 0; e < 8; e++) acc[e] += __shfl_down(acc[e], off);
  }
  if (lane == 0) {
    float l[8];
#pragma unroll
    for (int e = 0; e < 8; e++) l[e] = acc[e] + rb[e];
    int i0 = 0; float v0 = l[0];
#pragma unroll
    for (int e = 1; e < 8; e++) if (l[e] > v0) { v0 = l[e]; i0 = e; }
    int i1 = -1; float v1 = -3.4e38f;
#pragma unroll
    for (int e = 0; e < 8; e++) if (e != i0 && l[e] > v1) { v1 = l[e]; i1 = e; }
    float p1 = expf(v1 - v0);
    float s = 1.0f + p1;
    topk_idx[t * 2] = i0; topk_idx[t * 2 + 1] = i1;
    topk_p[t * 2] = 1.0f / s; topk_p[t * 2 + 1] = p1 / s;
  }
}

// ---------------- compaction phase 1: per-chunk per-expert counts ----------------
__global__ __launch_bounds__(256) void count_kernel(const int* __restrict__ topk_idx,
                                                    int* __restrict__ chunkcnt) {  // [NCHUNK][E]
  const int b = blockIdx.x, tid = threadIdx.x, lane = tid & 63, w = tid >> 6;
  const int t = b * 256 + tid;
  const int i0 = topk_idx[t * 2], i1 = topk_idx[t * 2 + 1];
  __shared__ int ws[4][E_NUM];
#pragma unroll
  for (int e = 0; e < E_NUM; e++) {
    unsigned long long m = __ballot(i0 == e || i1 == e);
    if (lane == 0) ws[w][e] = (int)__popcll(m);
  }
  __syncthreads();
  if (tid < E_NUM)
    chunkcnt[b * E_NUM + tid] = ws[0][tid] + ws[1][tid] + ws[2][tid] + ws[3][tid];
}

// ---------------- compaction phase 2: prefix + scatter (deterministic) ----------------
__global__ __launch_bounds__(256) void scatter_kernel(const int* __restrict__ topk_idx,
                                                      const float* __restrict__ topk_p,
                                                      const int* __restrict__ chunkcnt,
                                                      int* __restrict__ slot_list,
                                                      float* __restrict__ prob_list,
                                                      int* __restrict__ counts) {
  const int e = blockIdx.x & 7, chunk = blockIdx.x >> 3;
  const int tid = threadIdx.x, lane = tid & 63, w = tid >> 6;
  int base = 0;
  for (int c = 0; c < chunk; ++c) base += chunkcnt[c * E_NUM + e];
  const int t = chunk * 256 + tid;
  const int i0 = topk_idx[t * 2], i1 = topk_idx[t * 2 + 1];
  int flag = 0, slot = 0; float p = 0.f;
  if (i0 == e)      { flag = 1; slot = t * 2;     p = topk_p[t * 2]; }
  else if (i1 == e) { flag = 1; slot = t * 2 + 1; p = topk_p[t * 2 + 1]; }
  unsigned long long m = __ballot(flag);
  __shared__ int wsum[4];
  if (lane == 0) wsum[w] = (int)__popcll(m);
  const int wpre = (int)__popcll(m & ((1ull << lane) - 1ull));
  __syncthreads();
  int wb = base;
#pragma unroll
  for (int j = 0; j < 4; j++) if (j < w) wb += wsum[j];
  if (flag) { slot_list[e * CAP + wb + wpre] = slot; prob_list[e * CAP + wb + wpre] = p; }
  if (chunk == NCHUNK - 1 && tid == 0)
    counts[e] = base + wsum[0] + wsum[1] + wsum[2] + wsum[3];
}

// ---------------- grouped GEMM1: hc = gelu(x @ w1 + b1) * p ----------------
// tile 128x128, BK=64, wave 64x64; A direct->VGPR double-banked (loaded right AFTER the
// barrier -> full-phase flight); B-only LDS dbuf 32KB; single barrier; T2 swizzle; XCD pin
// flat grid 4096: e=bid&7; g=bid>>3: cx=g&15, rt=g>>4 (0..31)
__global__ __launch_bounds__(256, 3) void gemm1_kernel(const u16* __restrict__ xb,
                                                       const u16* __restrict__ w1t,   // [E][H][D]
                                                       const float* __restrict__ b1,  // [E][H]
                                                       const int* __restrict__ slot_list,
                                                       const float* __restrict__ prob_list,
                                                       const int* __restrict__ counts,
                                                       u16* __restrict__ hbufc) {     // [NSLOT][H] compacted
  const int e  = blockIdx.x & 7;
  const int g  = blockIdx.x >> 3;
  const int cx = g & 15;
  const int rt = g >> 4;           // 0..31
  const int cnt = counts[e];
  const int rbase = rt * 128;
  if (rbase >= cnt) return;
  int ebase = 0;
#pragma unroll
  for (int j = 0; j < E_NUM; j++) if (j < e) ebase += counts[j];
  const int n0 = cx * 128;

  __shared__ __align__(16) u16 Bt[2][128 * 64];   // 32 KB

  const int tid = threadIdx.x, lane = tid & 63, wid = tid >> 6;
  const int wr = wid >> 1, wc = wid & 1;
  const int lrow = lane & 15, lk = lane >> 4;

  // A direct pointers: 4 m-frags (gathered token rows); {lrow,lk} lanes form 64B segments
  const u16* aptr[4];
#pragma unroll
  for (int mf = 0; mf < 4; mf++) {
    const int r = rbase + wr * 64 + mf * 16 + lrow;
    int tok = 0;
    if (r < cnt) tok = slot_list[e * CAP + r] >> 1;
    aptr[mf] = xb + (size_t)tok * D_DIM + lk * 8;
  }

  // B staging: 1024 16B-chunks; 4/thread; pre-permuted source (T2 both-sides)
  const u16* pb[4]; int lob[4];
#pragma unroll
  for (int j = 0; j < 4; j++) {
    const int gch = j * 256 + tid;            // 0..1023
    const int row = gch >> 3, c = gch & 7;
    const int ck = (c ^ (row & 7)) << 3;
    pb[j] = w1t + ((size_t)e * H_DIM + n0 + row) * D_DIM + ck;
    lob[j] = gch << 3;
  }

  int boff[4][2];
#pragma unroll
  for (int nf = 0; nf < 4; nf++) {
    const int r = wc * 64 + nf * 16 + lrow;
#pragma unroll
    for (int ks = 0; ks < 2; ks++)
      boff[nf][ks] = r * 64 + (((ks * 4 + lk) ^ (r & 7)) << 3);
  }

  f32x4 acc[4][4];
#pragma unroll
  for (int i = 0; i < 4; i++)
#pragma unroll
    for (int j = 0; j < 4; j++) acc[i][j] = (f32x4){0.f, 0.f, 0.f, 0.f};

  auto stageB = [&](int k0, u16* dst) {
#pragma unroll
    for (int j = 0; j < 4; j++) gload16(pb[j] + k0, dst + lob[j]);
  };
  uint4 aA[4][2], aB[4][2];
  auto loadA = [&](int k0, uint4 (&bank)[4][2]) {
#pragma unroll
    for (int mf = 0; mf < 4; mf++) {
      bank[mf][0] = *(const uint4*)(aptr[mf] + k0);
      bank[mf][1] = *(const uint4*)(aptr[mf] + k0 + 32);
    }
  };

  const int nt = D_DIM / 64;   // 8
  stageB(0, Bt[0]);
  loadA(0, aA);

  auto step = [&](int t, uint4 (&ac)[4][2], uint4 (&an)[4][2], u16* lcur, u16* lnext) {
    asm volatile("s_waitcnt vmcnt(0)" ::: "memory");   // stage(t)+A(t) resident
    __builtin_amdgcn_sched_barrier(0);
    __builtin_amdgcn_s_barrier();                      // all waves see slot cur; slot next free
    if (t + 1 < nt) { stageB((t + 1) * 64, lnext); loadA((t + 1) * 64, an); }  // full-phase flight
    bf16x8 bfr[4][2];
#pragma unroll
    for (int nf = 0; nf < 4; nf++) {
      bfr[nf][0] = *(const bf16x8*)(lcur + boff[nf][0]);
      bfr[nf][1] = *(const bf16x8*)(lcur + boff[nf][1]);
    }
    asm volatile("s_waitcnt lgkmcnt(0)" ::: "memory"); // slot-cur reads drained before next barrier
    __builtin_amdgcn_sched_barrier(0);
    __builtin_amdgcn_s_setprio(1);
#pragma unroll
    for (int ks = 0; ks < 2; ks++)
#pragma unroll
      for (int mf = 0; mf < 4; mf++) {
        bf16x8 av = __builtin_bit_cast(bf16x8, ac[mf][ks]);
#pragma unroll
        for (int nf = 0; nf < 4; nf++)
          acc[mf][nf] = __builtin_amdgcn_mfma_f32_16x16x32_bf16(av, bfr[nf][ks], acc[mf][nf], 0, 0, 0);
      }
    __builtin_amdgcn_s_setprio(0);
  };

  for (int t2 = 0; t2 < nt; t2 += 2) {   // static banks/slots (rule #20)
    step(t2,     aA, aB, Bt[0], Bt[1]);
    step(t2 + 1, aB, aA, Bt[1], Bt[0]);
  }

  float bias[4];
#pragma unroll
  for (int nf = 0; nf < 4; nf++) bias[nf] = b1[e * H_DIM + n0 + wc * 64 + nf * 16 + lrow];
#pragma unroll
  for (int mf = 0; mf < 4; mf++) {
#pragma unroll
    for (int reg = 0; reg < 4; reg++) {
      const int rloc = wr * 64 + mf * 16 + lk * 4 + reg;
      const int grow = rbase + rloc;
      if (grow < cnt) {
        const float p = prob_list[e * CAP + grow];
        u16* dst = hbufc + (size_t)(ebase + grow) * H_DIM + n0 + wc * 64 + lrow;
#pragma unroll
        for (int nf = 0; nf < 4; nf++) {
          float v = acc[mf][nf][reg] + bias[nf];
          dst[nf * 16] = f2bf(gelu_fast(v) * p);
        }
      }
    }
  }
}

// ---------------- grouped GEMM2: out[t] += hc @ w2 + p*b2 (atomic f32, 2 addends) -------
// tile 64x64, BK=64, wave 32x32; A(hbufc)->VGPR double-banked; B-only LDS dbuf 16KB;
// ~1024 active blocks = 4/CU; single barrier; T2 swizzle; XCD pin
// flat grid 4096: e=bid&7; g=bid>>3: cx=g&7, rt=g>>3 (0..63)
__global__ __launch_bounds__(256, 4) void gemm2_kernel(const u16* __restrict__ hbufc, // [NSLOT][H] compacted
                                                       const u16* __restrict__ w2t,   // [E][D][H]
                                                       const float* __restrict__ b2,  // [E][D]
                                                       const int* __restrict__ slot_list,
                                                       const float* __restrict__ prob_list,
                                                       const int* __restrict__ counts,
                                                       float* __restrict__ out) {     // [T][D]
  const int e  = blockIdx.x & 7;
  const int g  = blockIdx.x >> 3;
  const int cx = g & 7;
  const int rt = g >> 3;           // 0..63
  const int cnt = counts[e];
  const int rbase = rt * 64;
  if (rbase >= cnt) return;
  int ebase = 0;
#pragma unroll
  for (int j = 0; j < E_NUM; j++) if (j < e) ebase += counts[j];
  const int n0 = cx * 64;

  __shared__ __align__(16) u16 Bt[2][64 * 64];    // 16 KB

  const int tid = threadIdx.x, lane = tid & 63, wid = tid >> 6;
  const int wr = wid >> 1, wc = wid & 1;
  const int lrow = lane & 15, lk = lane >> 4;

  const u16* aptr[2];
#pragma unroll
  for (int mf = 0; mf < 2; mf++) {
    const int r = rbase + wr * 32 + mf * 16 + lrow;
    const int cr = (r < cnt) ? (ebase + r) : 0;   // compacted, contiguous per expert
    aptr[mf] = hbufc + (size_t)cr * H_DIM + lk * 8;
  }

  const u16* pb[2]; int lob[2];
#pragma unroll
  for (int j = 0; j < 2; j++) {
    const int gch = j * 256 + tid;            // 0..511
    const int row = gch >> 3, c = gch & 7;
    const int ck = (c ^ (row & 7)) << 3;
    pb[j] = w2t + ((size_t)e * D_DIM + n0 + row) * H_DIM + ck;
    lob[j] = gch << 3;
  }

  int boff[2][2];
#pragma unroll
  for (int nf = 0; nf < 2; nf++) {
    const int r = wc * 32 + nf * 16 + lrow;
#pragma unroll
    for (int ks = 0; ks < 2; ks++)
      boff[nf][ks] = r * 64 + (((ks * 4 + lk) ^ (r & 7)) << 3);
  }

  f32x4 acc[2][2];
#pragma unroll
  for (int i = 0; i < 2; i++)
#pragma unroll
    for (int j = 0; j < 2; j++) acc[i][j] = (f32x4){0.f, 0.f, 0.f, 0.f};

  auto stageB = [&](int k0, u16* dst) {
#pragma unroll
    for (int j = 0; j < 2; j++) gload16(pb[j] + k0, dst + lob[j]);
  };
  uint4 aA[2][2], aB[2][2];
  auto loadA = [&](int k0, uint4 (&bank)[2][2]) {
#pragma unroll
    for (int mf = 0; mf < 2; mf++) {
      bank[mf][0] = *(const uint4*)(aptr[mf] + k0);
      bank[mf][1] = *(const uint4*)(aptr[mf] + k0 + 32);
    }
  };

  const int nt = H_DIM / 64;   // 32
  stageB(0, Bt[0]);
  loadA(0, aA);

  auto step = [&](int t, uint4 (&ac)[2][2], uint4 (&an)[2][2], u16* lcur, u16* lnext) {
    asm volatile("s_waitcnt vmcnt(0)" ::: "memory");
    __builtin_amdgcn_sched_barrier(0);
    __builtin_amdgcn_s_barrier();
    if (t + 1 < nt) { stageB((t + 1) * 64, lnext); loadA((t + 1) * 64, an); }
    bf16x8 bfr[2][2];
#pragma unroll
    for (int nf = 0; nf < 2; nf++) {
      bfr[nf][0] = *(const bf16x8*)(lcur + boff[nf][0]);
      bfr[nf][1] = *(const bf16x8*)(lcur + boff[nf][1]);
    }
    asm volatile("s_waitcnt lgkmcnt(0)" ::: "memory");
    __builtin_amdgcn_sched_barrier(0);
    __builtin_amdgcn_s_setprio(1);
#pragma unroll
    for (int ks = 0; ks < 2; ks++)
#pragma unroll
      for (int mf = 0; mf < 2; mf++) {
        bf16x8 av = __builtin_bit_cast(bf16x8, ac[mf][ks]);
#pragma unroll
        for (int nf = 0; nf < 2; nf++)
          acc[mf][nf] = __builtin_amdgcn_mfma_f32_16x16x32_bf16(av, bfr[nf][ks], acc[mf][nf], 0, 0, 0);
      }
    __builtin_amdgcn_s_setprio(0);
  };

  for (int t2 = 0; t2 < nt; t2 += 2) {   // static banks/slots
    step(t2,     aA, aB, Bt[0], Bt[1]);
    step(t2 + 1, aB, aA, Bt[1], Bt[0]);
  }

  // epilogue: out[token] += acc + p*b2 (exactly 2 atomic addends per element -> deterministic)
#pragma unroll
  for (int mf = 0; mf < 2; mf++) {
#pragma unroll
    for (int reg = 0; reg < 4; reg++) {
      const int rloc = wr * 32 + mf * 16 + lk * 4 + reg;
      const int grow = rbase + rloc;
      if (grow < cnt) {
        const int slot = slot_list[e * CAP + grow];
        const float p  = prob_list[e * CAP + grow];
        float* dst = out + (size_t)(slot >> 1) * D_DIM + n0 + wc * 32 + lrow;
#pragma unroll
        for (int nf = 0; nf < 2; nf++) {
          float v = acc[mf][nf][reg] + p * b2[e * D_DIM + n0 + wc * 32 + nf * 16 + lrow];
          atomicAdd(&dst[nf * 16], v);
        }
      }
    }
  }
}

extern "C" void kernel_launch(void* const* d_in, const int* in_sizes, int n_in,
                              void* d_out, int out_size, void* d_ws, size_t ws_size,
                              hipStream_t stream) {
  const float* x  = (const float*)d_in[0];
  const float* w1 = (const float*)d_in[1];
  const float* w2 = (const float*)d_in[2];
  const float* b1 = (const float*)d_in[3];
  const float* b2 = (const float*)d_in[4];
  const float* rw = (const float*)d_in[5];
  const float* rb = (const float*)d_in[6];
  float* out = (float*)d_out;

  char* ws = (char*)d_ws;
  size_t off = 0;
  auto alloc = [&](size_t bytes) -> void* {
    void* p = ws + off;
    off = (off + bytes + 255) & ~(size_t)255;
    return p;
  };
  int*   counts    = (int*)alloc(E_NUM * 4);
  int*   chunkcnt  = (int*)alloc(NCHUNK * E_NUM * 4);
  int*   slot_list = (int*)alloc((size_t)E_NUM * CAP * 4);
  float* prob_list = (float*)alloc((size_t)E_NUM * CAP * 4);
  int*   topk_idx  = (int*)alloc((size_t)T_TOKENS * 2 * 4);
  float* topk_p    = (float*)alloc((size_t)T_TOKENS * 2 * 4);
  u16*   xb        = (u16*)alloc((size_t)T_TOKENS * D_DIM * 2);
  u16*   w1t       = (u16*)alloc((size_t)E_NUM * H_DIM * D_DIM * 2);
  u16*   w2t       = (u16*)alloc((size_t)E_NUM * H_DIM * D_DIM * 2);
  u16*   hbufc     = (u16*)alloc((size_t)NSLOT * H_DIM * 2);

  transpose_both_kernel<<<4096, 256, 0, stream>>>(w1, w2, w1t, w2t);
  router_kernel<<<T_TOKENS / 4, 256, 0, stream>>>(x, rw, rb, topk_idx, topk_p, xb, out);
  count_kernel<<<NCHUNK, 256, 0, stream>>>(topk_idx, chunkcnt);
  scatter_kernel<<<NCHUNK * E_NUM, 256, 0, stream>>>(topk_idx, topk_p, chunkcnt, slot_list, prob_list, counts);
  gemm1_kernel<<<E_NUM * 16 * 32, 256, 0, stream>>>(xb, w1t, b1, slot_list, prob_list, counts, hbufc);
  gemm2_kernel<<<E_NUM * 8 * 64, 256, 0, stream>>>(hbufc, w2t, b2, slot_list, prob_list, counts, out);
}

// Round 13
// 132.347 us; speedup vs baseline: 1.6497x; 1.6497x over previous
//
#include <hip/hip_runtime.h>
#include <math.h>

typedef unsigned short u16;
typedef __bf16 bf16x8 __attribute__((ext_vector_type(8)));
typedef float f32x4 __attribute__((ext_vector_type(4)));

#define T_TOKENS 4096   // B*S
#define D_DIM    512
#define H_DIM    2048
#define E_NUM    8
#define CAP      4096   // per-expert worst-case capacity
#define NSLOT    (T_TOKENS * 2)
#define NCHUNK   16     // compaction chunks of 256 tokens

__device__ __forceinline__ u16 f2bf(float f) {
  unsigned int u = __builtin_bit_cast(unsigned int, f);
  u = (u + 0x7fffu + ((u >> 16) & 1u)) >> 16;   // RNE
  return (u16)u;
}

__device__ __forceinline__ void gload16(const void* g, void* l) {
  __builtin_amdgcn_global_load_lds(
      (__attribute__((address_space(1))) void*)(g),
      (__attribute__((address_space(3))) void*)(l), 16, 0, 0);
}

// gelu(v) ~= v * sigmoid(v*(1.59576912 + 0.071354817*v^2)); rcp instead of slow f32 div
__device__ __forceinline__ float gelu_fast(float v) {
  float u = v * __fmaf_rn(0.071354817f, v * v, 1.59576912f);
  float e = __expf(-u);
  return v * __builtin_amdgcn_rcpf(1.0f + e);
}

// ---------------- both weights: f32 [E][R][C] -> bf16 [E][C][R], one launch ----------------
__global__ __launch_bounds__(256) void transpose_both_kernel(const float* __restrict__ w1,
                                                             const float* __restrict__ w2,
                                                             u16* __restrict__ w1t,
                                                             u16* __restrict__ w2t) {
  __shared__ float tile[64][67];
  int bid = blockIdx.x;
  const float* in; u16* out; int R, C;
  if (bid < 2048) { in = w1; out = w1t; R = D_DIM; C = H_DIM; }
  else            { bid -= 2048; in = w2; out = w2t; R = H_DIM; C = D_DIM; }
  const int e = bid >> 8;
  const int t = bid & 255;
  const int nCx = C >> 6;
  const int c0 = (t % nCx) * 64, r0 = (t / nCx) * 64;
  const float* src = in + (size_t)e * D_DIM * H_DIM;
  u16* dst = out + (size_t)e * D_DIM * H_DIM;
  const int tid = threadIdx.x;
  {
    const int row = tid >> 2, cc = (tid & 3) * 16;
    const float* s = src + (size_t)(r0 + row) * C + c0 + cc;
#pragma unroll
    for (int j = 0; j < 4; j++)
      *(float4*)(&tile[row][cc + 4 * j]) = *(const float4*)(s + 4 * j);
  }
  __syncthreads();
  {
    const int c = tid >> 2, rc = (tid & 3) * 16;
    u16 buf[16];
#pragma unroll
    for (int j = 0; j < 16; j++) buf[j] = f2bf(tile[rc + j][c]);
    u16* d = dst + (size_t)(c0 + c) * R + r0 + rc;
    *(uint4*)(d)     = *(uint4*)(&buf[0]);
    *(uint4*)(d + 8) = *(uint4*)(&buf[8]);
  }
}

// ---------------- router + x->bf16 + zero(out) ----------------
__global__ __launch_bounds__(256) void router_kernel(const float* __restrict__ x,
                                                     const float* __restrict__ rw,
                                                     const float* __restrict__ rb,
                                                     int* __restrict__ topk_idx,
                                                     float* __restrict__ topk_p,
                                                     u16* __restrict__ xb,
                                                     float* __restrict__ outz) {
  {
    float4 z = {0.f, 0.f, 0.f, 0.f};
    float4* o = (float4*)(outz + (size_t)blockIdx.x * 2048);
    o[threadIdx.x] = z;
    o[threadIdx.x + 256] = z;
  }
  const int lane = threadIdx.x & 63;
  const int t = blockIdx.x * 4 + (threadIdx.x >> 6);
  const float* xr = x + (size_t)t * D_DIM + lane * 8;
  float xv[8];
  *(float4*)(&xv[0]) = *(const float4*)(xr);
  *(float4*)(&xv[4]) = *(const float4*)(xr + 4);
  ushort4 o0, o1;
  o0.x = f2bf(xv[0]); o0.y = f2bf(xv[1]); o0.z = f2bf(xv[2]); o0.w = f2bf(xv[3]);
  o1.x = f2bf(xv[4]); o1.y = f2bf(xv[5]); o1.z = f2bf(xv[6]); o1.w = f2bf(xv[7]);
  ushort4* xo = (ushort4*)(xb + (size_t)t * D_DIM + lane * 8);
  xo[0] = o0; xo[1] = o1;

  float acc[8] = {0.f,0.f,0.f,0.f,0.f,0.f,0.f,0.f};
#pragma unroll
  for (int j = 0; j < 8; j++) {
    const float4* w = (const float4*)(rw + (size_t)(lane * 8 + j) * E_NUM);
    float4 w0 = w[0], w1 = w[1];
    acc[0] += xv[j] * w0.x; acc[1] += xv[j] * w0.y;
    acc[2] += xv[j] * w0.z; acc[3] += xv[j] * w0.w;
    acc[4] += xv[j] * w1.x; acc[5] += xv[j] * w1.y;
    acc[6] += xv[j] * w1.z; acc[7] += xv[j] * w1.w;
  }
#pragma unroll
  for (int off = 32; off > 0; off >>= 1) {
#pragma unroll
    for (int e = 0; e < 8; e++) acc[e] += __shfl_down(acc[e], off);
  }
  if (lane == 0) {
    float l[8];
#pragma unroll
    for (int e = 0; e < 8; e++) l[e] = acc[e] + rb[e];
    int i0 = 0; float v0 = l[0];
#pragma unroll
    for (int e = 1; e < 8; e++) if (l[e] > v0) { v0 = l[e]; i0 = e; }
    int i1 = -1; float v1 = -3.4e38f;
#pragma unroll
    for (int e = 0; e < 8; e++) if (e != i0 && l[e] > v1) { v1 = l[e]; i1 = e; }
    float p1 = expf(v1 - v0);
    float s = 1.0f + p1;
    topk_idx[t * 2] = i0; topk_idx[t * 2 + 1] = i1;
    topk_p[t * 2] = 1.0f / s; topk_p[t * 2 + 1] = p1 / s;
  }
}

// ---------------- compaction phase 1: per-chunk per-expert counts ----------------
__global__ __launch_bounds__(256) void count_kernel(const int* __restrict__ topk_idx,
                                                    int* __restrict__ chunkcnt) {  // [NCHUNK][E]
  const int b = blockIdx.x, tid = threadIdx.x, lane = tid & 63, w = tid >> 6;
  const int t = b * 256 + tid;
  const int i0 = topk_idx[t * 2], i1 = topk_idx[t * 2 + 1];
  __shared__ int ws[4][E_NUM];
#pragma unroll
  for (int e = 0; e < E_NUM; e++) {
    unsigned long long m = __ballot(i0 == e || i1 == e);
    if (lane == 0) ws[w][e] = (int)__popcll(m);
  }
  __syncthreads();
  if (tid < E_NUM)
    chunkcnt[b * E_NUM + tid] = ws[0][tid] + ws[1][tid] + ws[2][tid] + ws[3][tid];
}

// ---------------- compaction phase 2: prefix + scatter (deterministic) ----------------
__global__ __launch_bounds__(256) void scatter_kernel(const int* __restrict__ topk_idx,
                                                      const float* __restrict__ topk_p,
                                                      const int* __restrict__ chunkcnt,
                                                      int* __restrict__ slot_list,
                                                      float* __restrict__ prob_list,
                                                      int* __restrict__ counts) {
  const int e = blockIdx.x & 7, chunk = blockIdx.x >> 3;
  const int tid = threadIdx.x, lane = tid & 63, w = tid >> 6;
  int base = 0;
  for (int c = 0; c < chunk; ++c) base += chunkcnt[c * E_NUM + e];
  const int t = chunk * 256 + tid;
  const int i0 = topk_idx[t * 2], i1 = topk_idx[t * 2 + 1];
  int flag = 0, slot = 0; float p = 0.f;
  if (i0 == e)      { flag = 1; slot = t * 2;     p = topk_p[t * 2]; }
  else if (i1 == e) { flag = 1; slot = t * 2 + 1; p = topk_p[t * 2 + 1]; }
  unsigned long long m = __ballot(flag);
  __shared__ int wsum[4];
  if (lane == 0) wsum[w] = (int)__popcll(m);
  const int wpre = (int)__popcll(m & ((1ull << lane) - 1ull));
  __syncthreads();
  int wb = base;
#pragma unroll
  for (int j = 0; j < 4; j++) if (j < w) wb += wsum[j];
  if (flag) { slot_list[e * CAP + wb + wpre] = slot; prob_list[e * CAP + wb + wpre] = p; }
  if (chunk == NCHUNK - 1 && tid == 0)
    counts[e] = base + wsum[0] + wsum[1] + wsum[2] + wsum[3];
}

// ---------------- grouped GEMM1: hc = gelu(x @ w1 + b1) * p (r7 loop + pin + compact) ----
// tile 64x128, BK=64, 2-buffer single-barrier loop, T2 swizzle, 48KB -> 3 blocks/CU
// flat grid 8192: e = bid&7 (XCD pin); g=bid>>3: cx = g&15, rt = g>>4 (0..63)
__global__ __launch_bounds__(256, 3) void gemm1_kernel(const u16* __restrict__ xb,
                                                       const u16* __restrict__ w1t,   // [E][H][D]
                                                       const float* __restrict__ b1,  // [E][H]
                                                       const int* __restrict__ slot_list,
                                                       const float* __restrict__ prob_list,
                                                       const int* __restrict__ counts,
                                                       u16* __restrict__ hbufc) {     // [NSLOT][H] compacted
  const int e  = blockIdx.x & 7;
  const int g  = blockIdx.x >> 3;
  const int cx = g & 15;
  const int rt = g >> 4;           // 0..63
  const int cnt = counts[e];
  const int rbase = rt * 64;
  if (rbase >= cnt) return;
  int ebase = 0;
#pragma unroll
  for (int j = 0; j < E_NUM; j++) if (j < e) ebase += counts[j];
  const int n0 = cx * 128;

  __shared__ __align__(16) u16 At[2][64 * 64];
  __shared__ __align__(16) u16 Bt[2][128 * 64];

  const int tid = threadIdx.x, lane = tid & 63, wid = tid >> 6;
  const int wr = wid >> 1, wc = wid & 1;
  const int lr8 = lane >> 3;
  const int sx = lane & 7;
  const int kperm = (sx ^ lr8) * 8;
  const int lrow = lane & 15, lk = lane >> 4;

  const u16* pa[2]; int loa[2];
#pragma unroll
  for (int i = 0; i < 2; i++) {
    const int row = (wid * 2 + i) * 8 + lr8;          // 0..63
    const int grow = rbase + row;
    int tok = 0;
    if (grow < cnt) tok = slot_list[e * CAP + grow] >> 1;
    pa[i] = xb + (size_t)tok * D_DIM + kperm;
    loa[i] = (wid * 2 + i) * 512;
  }
  const u16* pb[4]; int lob[4];
#pragma unroll
  for (int i = 0; i < 4; i++) {
    const int row = (wid * 4 + i) * 8 + lr8;          // 0..127
    pb[i] = w1t + ((size_t)e * H_DIM + n0 + row) * D_DIM + kperm;
    lob[i] = (wid * 4 + i) * 512;
  }

  f32x4 acc[2][4];
#pragma unroll
  for (int i = 0; i < 2; i++)
#pragma unroll
    for (int j = 0; j < 4; j++) acc[i][j] = (f32x4){0.f, 0.f, 0.f, 0.f};

  auto stage = [&](int k0, int b) {   // 6 gload_lds per thread
#pragma unroll
    for (int i = 0; i < 2; i++) gload16(pa[i] + k0, &At[b][loa[i]]);
#pragma unroll
    for (int i = 0; i < 4; i++) gload16(pb[i] + k0, &Bt[b][lob[i]]);
  };

  stage(0, 0);
  const int nt = D_DIM / 64;   // 8
  int cur = 0;
  for (int t = 0; t < nt; ++t) {
    asm volatile("s_waitcnt vmcnt(0)" ::: "memory");   // stage(t) resident (issued last step)
    __builtin_amdgcn_sched_barrier(0);
    __builtin_amdgcn_s_barrier();                      // all waves: buf[cur] ready, buf[cur^1] free
    if (t + 1 < nt) stage((t + 1) * 64, cur ^ 1);      // issue early; hides under ds_read+MFMA
    bf16x8 afr[2][2], bfr[4][2];
#pragma unroll
    for (int ks = 0; ks < 2; ks++) {
#pragma unroll
      for (int fq = 0; fq < 2; fq++)
        afr[fq][ks] = *(const bf16x8*)(&At[cur][(wr * 32 + fq * 16 + lrow) * 64 + ((ks * 4 + lk) ^ sx) * 8]);
#pragma unroll
      for (int fq = 0; fq < 4; fq++)
        bfr[fq][ks] = *(const bf16x8*)(&Bt[cur][(wc * 64 + fq * 16 + lrow) * 64 + ((ks * 4 + lk) ^ sx) * 8]);
    }
    asm volatile("s_waitcnt lgkmcnt(0)" ::: "memory"); // reads of buf[cur] drained before next barrier
    __builtin_amdgcn_sched_barrier(0);
    __builtin_amdgcn_s_setprio(1);
#pragma unroll
    for (int ks = 0; ks < 2; ks++)
#pragma unroll
      for (int fr = 0; fr < 2; fr++)
#pragma unroll
        for (int fc = 0; fc < 4; fc++)
          acc[fr][fc] = __builtin_amdgcn_mfma_f32_16x16x32_bf16(afr[fr][ks], bfr[fc][ks], acc[fr][fc], 0, 0, 0);
    __builtin_amdgcn_s_setprio(0);
    cur ^= 1;
  }

  float bias[4];
#pragma unroll
  for (int fc = 0; fc < 4; fc++) bias[fc] = b1[e * H_DIM + n0 + wc * 64 + fc * 16 + lrow];
#pragma unroll
  for (int fr = 0; fr < 2; fr++) {
#pragma unroll
    for (int reg = 0; reg < 4; reg++) {
      const int rloc = wr * 32 + fr * 16 + lk * 4 + reg;
      const int grow = rbase + rloc;
      if (grow < cnt) {
        const float p = prob_list[e * CAP + grow];
        u16* dst = hbufc + (size_t)(ebase + grow) * H_DIM + n0 + wc * 64 + lrow;
#pragma unroll
        for (int fc = 0; fc < 4; fc++) {
          float v = acc[fr][fc][reg] + bias[fc];
          dst[fc * 16] = f2bf(gelu_fast(v) * p);
        }
      }
    }
  }
}

// ---------------- grouped GEMM2: out[t] += hc @ w2 + p*b2 (atomic f32, 2 addends) -------
// tile 32x128, BK=64, 2-buffer single-barrier loop, T2 swizzle, 40KB -> 4 blocks/CU
// waves: 2M x 2N, wave-out 16x64; ~1024 active blocks
// flat grid 4096: e = bid&7 (XCD pin); g=bid>>3: cx = g&3, rt = g>>2 (0..127)
__global__ __launch_bounds__(256, 4) void gemm2_kernel(const u16* __restrict__ hbufc, // [NSLOT][H] compacted
                                                       const u16* __restrict__ w2t,   // [E][D][H]
                                                       const float* __restrict__ b2,  // [E][D]
                                                       const int* __restrict__ slot_list,
                                                       const float* __restrict__ prob_list,
                                                       const int* __restrict__ counts,
                                                       float* __restrict__ out) {     // [T][D]
  const int e  = blockIdx.x & 7;
  const int g  = blockIdx.x >> 3;
  const int cx = g & 3;
  const int rt = g >> 2;           // 0..127
  const int cnt = counts[e];
  const int rbase = rt * 32;
  if (rbase >= cnt) return;
  int ebase = 0;
#pragma unroll
  for (int j = 0; j < E_NUM; j++) if (j < e) ebase += counts[j];
  const int n0 = cx * 128;

  __shared__ __align__(16) u16 At[2][32 * 64];    // 8 KB
  __shared__ __align__(16) u16 Bt[2][128 * 64];   // 32 KB

  const int tid = threadIdx.x, lane = tid & 63, wid = tid >> 6;
  const int wr = wid >> 1, wc = wid & 1;
  const int lrow = lane & 15, lk = lane >> 4;

  // A staging: 256 16B-chunks (32 rows x 8); 1 per thread; pre-permuted source (T2)
  const u16* pa; int loa;
  {
    const int row = tid >> 3, c = tid & 7;
    const int ck = (c ^ (row & 7)) << 3;
    const int grow = rbase + row;
    const int cr = (grow < cnt) ? (ebase + grow) : 0;
    pa = hbufc + (size_t)cr * H_DIM + ck;
    loa = tid << 3;
  }
  // B staging: 1024 chunks (128 rows x 8); 4 per thread
  const u16* pb[4]; int lob[4];
#pragma unroll
  for (int j = 0; j < 4; j++) {
    const int gch = j * 256 + tid;            // 0..1023
    const int row = gch >> 3, c = gch & 7;
    const int ck = (c ^ (row & 7)) << 3;
    pb[j] = w2t + ((size_t)e * D_DIM + n0 + row) * H_DIM + ck;
    lob[j] = gch << 3;
  }

  // frag read offsets (swizzled)
  int aoff[2], boff[4][2];
  {
    const int r = wr * 16 + lrow;
#pragma unroll
    for (int ks = 0; ks < 2; ks++)
      aoff[ks] = r * 64 + (((ks * 4 + lk) ^ (r & 7)) << 3);
  }
#pragma unroll
  for (int nf = 0; nf < 4; nf++) {
    const int r = wc * 64 + nf * 16 + lrow;
#pragma unroll
    for (int ks = 0; ks < 2; ks++)
      boff[nf][ks] = r * 64 + (((ks * 4 + lk) ^ (r & 7)) << 3);
  }

  f32x4 acc[4];
#pragma unroll
  for (int j = 0; j < 4; j++) acc[j] = (f32x4){0.f, 0.f, 0.f, 0.f};

  auto stage = [&](int k0, int b) {   // 5 gload_lds per thread
    gload16(pa + k0, &At[b][loa]);
#pragma unroll
    for (int j = 0; j < 4; j++) gload16(pb[j] + k0, &Bt[b][lob[j]]);
  };

  stage(0, 0);
  const int nt = H_DIM / 64;   // 32
  int cur = 0;
  for (int t = 0; t < nt; ++t) {
    asm volatile("s_waitcnt vmcnt(0)" ::: "memory");
    __builtin_amdgcn_sched_barrier(0);
    __builtin_amdgcn_s_barrier();
    if (t + 1 < nt) stage((t + 1) * 64, cur ^ 1);
    bf16x8 afr[2], bfr[4][2];
#pragma unroll
    for (int ks = 0; ks < 2; ks++) {
      afr[ks] = *(const bf16x8*)(&At[cur][aoff[ks]]);
#pragma unroll
      for (int nf = 0; nf < 4; nf++)
        bfr[nf][ks] = *(const bf16x8*)(&Bt[cur][boff[nf][ks]]);
    }
    asm volatile("s_waitcnt lgkmcnt(0)" ::: "memory");
    __builtin_amdgcn_sched_barrier(0);
    __builtin_amdgcn_s_setprio(1);
#pragma unroll
    for (int ks = 0; ks < 2; ks++)
#pragma unroll
      for (int nf = 0; nf < 4; nf++)
        acc[nf] = __builtin_amdgcn_mfma_f32_16x16x32_bf16(afr[ks], bfr[nf][ks], acc[nf], 0, 0, 0);
    __builtin_amdgcn_s_setprio(0);
    cur ^= 1;
  }

  // epilogue: out[token] += acc + p*b2 (exactly 2 atomic addends per element -> deterministic)
#pragma unroll
  for (int reg = 0; reg < 4; reg++) {
    const int rloc = wr * 16 + lk * 4 + reg;
    const int grow = rbase + rloc;
    if (grow < cnt) {
      const int slot = slot_list[e * CAP + grow];
      const float p  = prob_list[e * CAP + grow];
      float* dst = out + (size_t)(slot >> 1) * D_DIM + n0 + wc * 64 + lrow;
#pragma unroll
      for (int nf = 0; nf < 4; nf++) {
        float v = acc[nf][reg] + p * b2[e * D_DIM + n0 + wc * 64 + nf * 16 + lrow];
        atomicAdd(&dst[nf * 16], v);
      }
    }
  }
}

extern "C" void kernel_launch(void* const* d_in, const int* in_sizes, int n_in,
                              void* d_out, int out_size, void* d_ws, size_t ws_size,
                              hipStream_t stream) {
  const float* x  = (const float*)d_in[0];
  const float* w1 = (const float*)d_in[1];
  const float* w2 = (const float*)d_in[2];
  const float* b1 = (const float*)d_in[3];
  const float* b2 = (const float*)d_in[4];
  const float* rw = (const float*)d_in[5];
  const float* rb = (const float*)d_in[6];
  float* out = (float*)d_out;

  char* ws = (char*)d_ws;
  size_t off = 0;
  auto alloc = [&](size_t bytes) -> void* {
    void* p = ws + off;
    off = (off + bytes + 255) & ~(size_t)255;
    return p;
  };
  int*   counts    = (int*)alloc(E_NUM * 4);
  int*   chunkcnt  = (int*)alloc(NCHUNK * E_NUM * 4);
  int*   slot_list = (int*)alloc((size_t)E_NUM * CAP * 4);
  float* prob_list = (float*)alloc((size_t)E_NUM * CAP * 4);
  int*   topk_idx  = (int*)alloc((size_t)T_TOKENS * 2 * 4);
  float* topk_p    = (float*)alloc((size_t)T_TOKENS * 2 * 4);
  u16*   xb        = (u16*)alloc((size_t)T_TOKENS * D_DIM * 2);
  u16*   w1t       = (u16*)alloc((size_t)E_NUM * H_DIM * D_DIM * 2);
  u16*   w2t       = (u16*)alloc((size_t)E_NUM * H_DIM * D_DIM * 2);
  u16*   hbufc     = (u16*)alloc((size_t)NSLOT * H_DIM * 2);

  transpose_both_kernel<<<4096, 256, 0, stream>>>(w1, w2, w1t, w2t);
  router_kernel<<<T_TOKENS / 4, 256, 0, stream>>>(x, rw, rb, topk_idx, topk_p, xb, out);
  count_kernel<<<NCHUNK, 256, 0, stream>>>(topk_idx, chunkcnt);
  scatter_kernel<<<NCHUNK * E_NUM, 256, 0, stream>>>(topk_idx, topk_p, chunkcnt, slot_list, prob_list, counts);
  gemm1_kernel<<<E_NUM * 16 * 64, 256, 0, stream>>>(xb, w1t, b1, slot_list, prob_list, counts, hbufc);
  gemm2_kernel<<<E_NUM * 4 * 128, 256, 0, stream>>>(hbufc, w2t, b2, slot_list, prob_list, counts, out);
}

// Round 14
// 118.764 us; speedup vs baseline: 1.8384x; 1.1144x over previous
//
#include <hip/hip_runtime.h>
#include <math.h>

typedef unsigned short u16;
typedef __bf16 bf16x8 __attribute__((ext_vector_type(8)));
typedef float f32x4 __attribute__((ext_vector_type(4)));

#define T_TOKENS 4096   // B*S
#define D_DIM    512
#define H_DIM    2048
#define E_NUM    8
#define CAP      4096   // per-expert worst-case capacity
#define NSLOT    (T_TOKENS * 2)

__device__ __forceinline__ u16 f2bf(float f) {
  unsigned int u = __builtin_bit_cast(unsigned int, f);
  u = (u + 0x7fffu + ((u >> 16) & 1u)) >> 16;   // RNE
  return (u16)u;
}

__device__ __forceinline__ void gload16(const void* g, void* l) {
  __builtin_amdgcn_global_load_lds(
      (__attribute__((address_space(1))) void*)(g),
      (__attribute__((address_space(3))) void*)(l), 16, 0, 0);
}

// gelu(v) ~= v * sigmoid(v*(1.59576912 + 0.071354817*v^2)); rcp instead of slow f32 div
__device__ __forceinline__ float gelu_fast(float v) {
  float u = v * __fmaf_rn(0.071354817f, v * v, 1.59576912f);
  float e = __expf(-u);
  return v * __builtin_amdgcn_rcpf(1.0f + e);
}

// ---------------- both weights: f32 [E][R][C] -> bf16 [E][C][R], one launch ----------------
__global__ __launch_bounds__(256) void transpose_both_kernel(const float* __restrict__ w1,
                                                             const float* __restrict__ w2,
                                                             u16* __restrict__ w1t,
                                                             u16* __restrict__ w2t) {
  __shared__ float tile[64][67];
  int bid = blockIdx.x;
  const float* in; u16* out; int R, C;
  if (bid < 2048) { in = w1; out = w1t; R = D_DIM; C = H_DIM; }
  else            { bid -= 2048; in = w2; out = w2t; R = H_DIM; C = D_DIM; }
  const int e = bid >> 8;
  const int t = bid & 255;
  const int nCx = C >> 6;
  const int c0 = (t % nCx) * 64, r0 = (t / nCx) * 64;
  const float* src = in + (size_t)e * D_DIM * H_DIM;
  u16* dst = out + (size_t)e * D_DIM * H_DIM;
  const int tid = threadIdx.x;
  {
    const int row = tid >> 2, cc = (tid & 3) * 16;
    const float* s = src + (size_t)(r0 + row) * C + c0 + cc;
#pragma unroll
    for (int j = 0; j < 4; j++)
      *(float4*)(&tile[row][cc + 4 * j]) = *(const float4*)(s + 4 * j);
  }
  __syncthreads();
  {
    const int c = tid >> 2, rc = (tid & 3) * 16;
    u16 buf[16];
#pragma unroll
    for (int j = 0; j < 16; j++) buf[j] = f2bf(tile[rc + j][c]);
    u16* d = dst + (size_t)(c0 + c) * R + r0 + rc;
    *(uint4*)(d)     = *(uint4*)(&buf[0]);
    *(uint4*)(d + 8) = *(uint4*)(&buf[8]);
  }
}

// ---------------- router + x->bf16 + zero(out) ----------------
__global__ __launch_bounds__(256) void router_kernel(const float* __restrict__ x,
                                                     const float* __restrict__ rw,
                                                     const float* __restrict__ rb,
                                                     int* __restrict__ topk_idx,
                                                     float* __restrict__ topk_p,
                                                     u16* __restrict__ xb,
                                                     float* __restrict__ outz) {
  {
    float4 z = {0.f, 0.f, 0.f, 0.f};
    float4* o = (float4*)(outz + (size_t)blockIdx.x * 2048);
    o[threadIdx.x] = z;
    o[threadIdx.x + 256] = z;
  }
  const int lane = threadIdx.x & 63;
  const int t = blockIdx.x * 4 + (threadIdx.x >> 6);
  const float* xr = x + (size_t)t * D_DIM + lane * 8;
  float xv[8];
  *(float4*)(&xv[0]) = *(const float4*)(xr);
  *(float4*)(&xv[4]) = *(const float4*)(xr + 4);
  ushort4 o0, o1;
  o0.x = f2bf(xv[0]); o0.y = f2bf(xv[1]); o0.z = f2bf(xv[2]); o0.w = f2bf(xv[3]);
  o1.x = f2bf(xv[4]); o1.y = f2bf(xv[5]); o1.z = f2bf(xv[6]); o1.w = f2bf(xv[7]);
  ushort4* xo = (ushort4*)(xb + (size_t)t * D_DIM + lane * 8);
  xo[0] = o0; xo[1] = o1;

  float acc[8] = {0.f,0.f,0.f,0.f,0.f,0.f,0.f,0.f};
#pragma unroll
  for (int j = 0; j < 8; j++) {
    const float4* w = (const float4*)(rw + (size_t)(lane * 8 + j) * E_NUM);
    float4 w0 = w[0], w1 = w[1];
    acc[0] += xv[j] * w0.x; acc[1] += xv[j] * w0.y;
    acc[2] += xv[j] * w0.z; acc[3] += xv[j] * w0.w;
    acc[4] += xv[j] * w1.x; acc[5] += xv[j] * w1.y;
    acc[6] += xv[j] * w1.z; acc[7] += xv[j] * w1.w;
  }
#pragma unroll
  for (int off = 32; off > 0; off >>= 1) {
#pragma unroll
    for (int e = 0; e < 8; e++) acc[e] += __shfl_down(acc[e], off);
  }
  if (lane == 0) {
    float l[8];
#pragma unroll
    for (int e = 0; e < 8; e++) l[e] = acc[e] + rb[e];
    int i0 = 0; float v0 = l[0];
#pragma unroll
    for (int e = 1; e < 8; e++) if (l[e] > v0) { v0 = l[e]; i0 = e; }
    int i1 = -1; float v1 = -3.4e38f;
#pragma unroll
    for (int e = 0; e < 8; e++) if (e != i0 && l[e] > v1) { v1 = l[e]; i1 = e; }
    float p1 = expf(v1 - v0);
    float s = 1.0f + p1;
    topk_idx[t * 2] = i0; topk_idx[t * 2 + 1] = i1;
    topk_p[t * 2] = 1.0f / s; topk_p[t * 2 + 1] = p1 / s;
  }
}

// ---------------- deterministic per-expert compaction (ballot scan, 8 blocks) ----------------
__global__ __launch_bounds__(256) void compact_kernel(const int* __restrict__ topk_idx,
                                                      const float* __restrict__ topk_p,
                                                      int* __restrict__ slot_list,
                                                      float* __restrict__ prob_list,
                                                      int* __restrict__ counts) {
  const int e = blockIdx.x;
  const int tid = threadIdx.x, lane = tid & 63, w = tid >> 6;
  __shared__ int wsum[4];
  __shared__ int sbase;
  if (tid == 0) sbase = 0;
  __syncthreads();
  for (int c0 = 0; c0 < T_TOKENS; c0 += 256) {
    const int t = c0 + tid;
    const int i0 = topk_idx[t * 2], i1 = topk_idx[t * 2 + 1];
    int flag = 0, slot = 0; float p = 0.f;
    if (i0 == e)      { flag = 1; slot = t * 2;     p = topk_p[t * 2]; }
    else if (i1 == e) { flag = 1; slot = t * 2 + 1; p = topk_p[t * 2 + 1]; }
    unsigned long long m = __ballot(flag);
    if (lane == 0) wsum[w] = (int)__popcll(m);
    const int wpre = (int)__popcll(m & ((1ull << lane) - 1ull));
    __syncthreads();
    int base = sbase;
#pragma unroll
    for (int j = 0; j < 4; j++) if (j < w) base += wsum[j];
    const int tot = wsum[0] + wsum[1] + wsum[2] + wsum[3];
    if (flag) { slot_list[e * CAP + base + wpre] = slot; prob_list[e * CAP + base + wpre] = p; }
    __syncthreads();
    if (tid == 0) sbase += tot;
  }
  __syncthreads();
  if (tid == 0) counts[e] = sbase;
}

// ---------------- grouped GEMM1: hc = gelu(x @ w1 + b1) * p (r7 loop + pin + compact) ----
// tile 64x128, BK=64, 2-buffer single-barrier loop, T2 swizzle, 48KB -> 3 blocks/CU
// flat grid 8192: e = bid&7 (XCD pin); g=bid>>3: cx = g&15, rt = g>>4 (0..63)
__global__ __launch_bounds__(256, 3) void gemm1_kernel(const u16* __restrict__ xb,
                                                       const u16* __restrict__ w1t,   // [E][H][D]
                                                       const float* __restrict__ b1,  // [E][H]
                                                       const int* __restrict__ slot_list,
                                                       const float* __restrict__ prob_list,
                                                       const int* __restrict__ counts,
                                                       u16* __restrict__ hbufc) {     // [NSLOT][H] compacted
  const int e  = blockIdx.x & 7;
  const int g  = blockIdx.x >> 3;
  const int cx = g & 15;
  const int rt = g >> 4;           // 0..63
  const int cnt = counts[e];
  const int rbase = rt * 64;
  if (rbase >= cnt) return;
  int ebase = 0;
#pragma unroll
  for (int j = 0; j < E_NUM; j++) if (j < e) ebase += counts[j];
  const int n0 = cx * 128;

  __shared__ __align__(16) u16 At[2][64 * 64];
  __shared__ __align__(16) u16 Bt[2][128 * 64];

  const int tid = threadIdx.x, lane = tid & 63, wid = tid >> 6;
  const int wr = wid >> 1, wc = wid & 1;
  const int lr8 = lane >> 3;
  const int sx = lane & 7;
  const int kperm = (sx ^ lr8) * 8;
  const int lrow = lane & 15, lk = lane >> 4;

  const u16* pa[2]; int loa[2];
#pragma unroll
  for (int i = 0; i < 2; i++) {
    const int row = (wid * 2 + i) * 8 + lr8;          // 0..63
    const int grow = rbase + row;
    int tok = 0;
    if (grow < cnt) tok = slot_list[e * CAP + grow] >> 1;
    pa[i] = xb + (size_t)tok * D_DIM + kperm;
    loa[i] = (wid * 2 + i) * 512;
  }
  const u16* pb[4]; int lob[4];
#pragma unroll
  for (int i = 0; i < 4; i++) {
    const int row = (wid * 4 + i) * 8 + lr8;          // 0..127
    pb[i] = w1t + ((size_t)e * H_DIM + n0 + row) * D_DIM + kperm;
    lob[i] = (wid * 4 + i) * 512;
  }

  f32x4 acc[2][4];
#pragma unroll
  for (int i = 0; i < 2; i++)
#pragma unroll
    for (int j = 0; j < 4; j++) acc[i][j] = (f32x4){0.f, 0.f, 0.f, 0.f};

  auto stage = [&](int k0, int b) {   // 6 gload_lds per thread
#pragma unroll
    for (int i = 0; i < 2; i++) gload16(pa[i] + k0, &At[b][loa[i]]);
#pragma unroll
    for (int i = 0; i < 4; i++) gload16(pb[i] + k0, &Bt[b][lob[i]]);
  };

  stage(0, 0);
  const int nt = D_DIM / 64;   // 8
  int cur = 0;
  for (int t = 0; t < nt; ++t) {
    asm volatile("s_waitcnt vmcnt(0)" ::: "memory");   // stage(t) resident (issued last step)
    __builtin_amdgcn_sched_barrier(0);
    __builtin_amdgcn_s_barrier();                      // all waves: buf[cur] ready, buf[cur^1] free
    if (t + 1 < nt) stage((t + 1) * 64, cur ^ 1);      // issue early; hides under ds_read+MFMA
    bf16x8 afr[2][2], bfr[4][2];
#pragma unroll
    for (int ks = 0; ks < 2; ks++) {
#pragma unroll
      for (int fq = 0; fq < 2; fq++)
        afr[fq][ks] = *(const bf16x8*)(&At[cur][(wr * 32 + fq * 16 + lrow) * 64 + ((ks * 4 + lk) ^ sx) * 8]);
#pragma unroll
      for (int fq = 0; fq < 4; fq++)
        bfr[fq][ks] = *(const bf16x8*)(&Bt[cur][(wc * 64 + fq * 16 + lrow) * 64 + ((ks * 4 + lk) ^ sx) * 8]);
    }
    asm volatile("s_waitcnt lgkmcnt(0)" ::: "memory"); // reads of buf[cur] drained before next barrier
    __builtin_amdgcn_sched_barrier(0);
    __builtin_amdgcn_s_setprio(1);
#pragma unroll
    for (int ks = 0; ks < 2; ks++)
#pragma unroll
      for (int fr = 0; fr < 2; fr++)
#pragma unroll
        for (int fc = 0; fc < 4; fc++)
          acc[fr][fc] = __builtin_amdgcn_mfma_f32_16x16x32_bf16(afr[fr][ks], bfr[fc][ks], acc[fr][fc], 0, 0, 0);
    __builtin_amdgcn_s_setprio(0);
    cur ^= 1;
  }

  float bias[4];
#pragma unroll
  for (int fc = 0; fc < 4; fc++) bias[fc] = b1[e * H_DIM + n0 + wc * 64 + fc * 16 + lrow];
#pragma unroll
  for (int fr = 0; fr < 2; fr++) {
#pragma unroll
    for (int reg = 0; reg < 4; reg++) {
      const int rloc = wr * 32 + fr * 16 + lk * 4 + reg;
      const int grow = rbase + rloc;
      if (grow < cnt) {
        const float p = prob_list[e * CAP + grow];
        u16* dst = hbufc + (size_t)(ebase + grow) * H_DIM + n0 + wc * 64 + lrow;
#pragma unroll
        for (int fc = 0; fc < 4; fc++) {
          float v = acc[fr][fc][reg] + bias[fc];
          dst[fc * 16] = f2bf(gelu_fast(v) * p);
        }
      }
    }
  }
}

// ---------------- grouped GEMM2: out[t] += hc @ w2 + p*b2 (atomic f32, 2 addends) -------
// tile 64x128, BK=64, single-barrier dbuf (r7 best), compacted A, XCD pin, 48KB -> 3/CU
// flat grid 2048: e = bid&7; g=bid>>3: cx = g&3, rt = g>>2 (0..63)
__global__ __launch_bounds__(256, 3) void gemm2_kernel(const u16* __restrict__ hbufc, // [NSLOT][H] compacted
                                                       const u16* __restrict__ w2t,   // [E][D][H]
                                                       const float* __restrict__ b2,  // [E][D]
                                                       const int* __restrict__ slot_list,
                                                       const float* __restrict__ prob_list,
                                                       const int* __restrict__ counts,
                                                       float* __restrict__ out) {     // [T][D]
  const int e  = blockIdx.x & 7;
  const int g  = blockIdx.x >> 3;
  const int cx = g & 3;
  const int rt = g >> 2;           // 0..63
  const int cnt = counts[e];
  const int rbase = rt * 64;
  if (rbase >= cnt) return;
  int ebase = 0;
#pragma unroll
  for (int j = 0; j < E_NUM; j++) if (j < e) ebase += counts[j];
  const int n0 = cx * 128;

  __shared__ __align__(16) u16 At[2][64 * 64];
  __shared__ __align__(16) u16 Bt[2][128 * 64];

  const int tid = threadIdx.x, lane = tid & 63, wid = tid >> 6;
  const int wr = wid >> 1, wc = wid & 1;
  const int lr8 = lane >> 3;
  const int sx = lane & 7;
  const int kperm = (sx ^ lr8) * 8;
  const int lrow = lane & 15, lk = lane >> 4;

  const u16* pa[2]; int loa[2];
#pragma unroll
  for (int i = 0; i < 2; i++) {
    const int row = (wid * 2 + i) * 8 + lr8;          // 0..63
    const int grow = rbase + row;
    const int cr = (grow < cnt) ? (ebase + grow) : 0; // compacted, contiguous per expert
    pa[i] = hbufc + (size_t)cr * H_DIM + kperm;
    loa[i] = (wid * 2 + i) * 512;
  }
  const u16* pb[4]; int lob[4];
#pragma unroll
  for (int i = 0; i < 4; i++) {
    const int row = (wid * 4 + i) * 8 + lr8;          // 0..127
    pb[i] = w2t + ((size_t)e * D_DIM + n0 + row) * H_DIM + kperm;
    lob[i] = (wid * 4 + i) * 512;
  }

  f32x4 acc[2][4];
#pragma unroll
  for (int i = 0; i < 2; i++)
#pragma unroll
    for (int j = 0; j < 4; j++) acc[i][j] = (f32x4){0.f, 0.f, 0.f, 0.f};

  auto stage = [&](int k0, int b) {   // 6 gload_lds per thread
#pragma unroll
    for (int i = 0; i < 2; i++) gload16(pa[i] + k0, &At[b][loa[i]]);
#pragma unroll
    for (int i = 0; i < 4; i++) gload16(pb[i] + k0, &Bt[b][lob[i]]);
  };

  stage(0, 0);
  const int nt = H_DIM / 64;   // 32
  int cur = 0;
  for (int t = 0; t < nt; ++t) {
    asm volatile("s_waitcnt vmcnt(0)" ::: "memory");
    __builtin_amdgcn_sched_barrier(0);
    __builtin_amdgcn_s_barrier();
    if (t + 1 < nt) stage((t + 1) * 64, cur ^ 1);
    bf16x8 afr[2][2], bfr[4][2];
#pragma unroll
    for (int ks = 0; ks < 2; ks++) {
#pragma unroll
      for (int fq = 0; fq < 2; fq++)
        afr[fq][ks] = *(const bf16x8*)(&At[cur][(wr * 32 + fq * 16 + lrow) * 64 + ((ks * 4 + lk) ^ sx) * 8]);
#pragma unroll
      for (int fq = 0; fq < 4; fq++)
        bfr[fq][ks] = *(const bf16x8*)(&Bt[cur][(wc * 64 + fq * 16 + lrow) * 64 + ((ks * 4 + lk) ^ sx) * 8]);
    }
    asm volatile("s_waitcnt lgkmcnt(0)" ::: "memory");
    __builtin_amdgcn_sched_barrier(0);
    __builtin_amdgcn_s_setprio(1);
#pragma unroll
    for (int ks = 0; ks < 2; ks++)
#pragma unroll
      for (int fr = 0; fr < 2; fr++)
#pragma unroll
        for (int fc = 0; fc < 4; fc++)
          acc[fr][fc] = __builtin_amdgcn_mfma_f32_16x16x32_bf16(afr[fr][ks], bfr[fc][ks], acc[fr][fc], 0, 0, 0);
    __builtin_amdgcn_s_setprio(0);
    cur ^= 1;
  }

  // epilogue: out[token] += acc + p*b2 (exactly 2 atomic addends per element -> deterministic)
#pragma unroll
  for (int fr = 0; fr < 2; fr++) {
#pragma unroll
    for (int reg = 0; reg < 4; reg++) {
      const int rloc = wr * 32 + fr * 16 + lk * 4 + reg;
      const int grow = rbase + rloc;
      if (grow < cnt) {
        const int slot = slot_list[e * CAP + grow];
        const float p  = prob_list[e * CAP + grow];
        float* dst = out + (size_t)(slot >> 1) * D_DIM + n0 + wc * 64 + lrow;
#pragma unroll
        for (int fc = 0; fc < 4; fc++) {
          float v = acc[fr][fc][reg] + p * b2[e * D_DIM + n0 + wc * 64 + fc * 16 + lrow];
          atomicAdd(&dst[fc * 16], v);
        }
      }
    }
  }
}

extern "C" void kernel_launch(void* const* d_in, const int* in_sizes, int n_in,
                              void* d_out, int out_size, void* d_ws, size_t ws_size,
                              hipStream_t stream) {
  const float* x  = (const float*)d_in[0];
  const float* w1 = (const float*)d_in[1];
  const float* w2 = (const float*)d_in[2];
  const float* b1 = (const float*)d_in[3];
  const float* b2 = (const float*)d_in[4];
  const float* rw = (const float*)d_in[5];
  const float* rb = (const float*)d_in[6];
  float* out = (float*)d_out;

  char* ws = (char*)d_ws;
  size_t off = 0;
  auto alloc = [&](size_t bytes) -> void* {
    void* p = ws + off;
    off = (off + bytes + 255) & ~(size_t)255;
    return p;
  };
  int*   counts    = (int*)alloc(E_NUM * 4);
  int*   slot_list = (int*)alloc((size_t)E_NUM * CAP * 4);
  float* prob_list = (float*)alloc((size_t)E_NUM * CAP * 4);
  int*   topk_idx  = (int*)alloc((size_t)T_TOKENS * 2 * 4);
  float* topk_p    = (float*)alloc((size_t)T_TOKENS * 2 * 4);
  u16*   xb        = (u16*)alloc((size_t)T_TOKENS * D_DIM * 2);
  u16*   w1t       = (u16*)alloc((size_t)E_NUM * H_DIM * D_DIM * 2);
  u16*   w2t       = (u16*)alloc((size_t)E_NUM * H_DIM * D_DIM * 2);
  u16*   hbufc     = (u16*)alloc((size_t)NSLOT * H_DIM * 2);

  transpose_both_kernel<<<4096, 256, 0, stream>>>(w1, w2, w1t, w2t);
  router_kernel<<<T_TOKENS / 4, 256, 0, stream>>>(x, rw, rb, topk_idx, topk_p, xb, out);
  compact_kernel<<<E_NUM, 256, 0, stream>>>(topk_idx, topk_p, slot_list, prob_list, counts);
  gemm1_kernel<<<E_NUM * 16 * 64, 256, 0, stream>>>(xb, w1t, b1, slot_list, prob_list, counts, hbufc);
  gemm2_kernel<<<E_NUM * 4 * 64, 256, 0, stream>>>(hbufc, w2t, b2, slot_list, prob_list, counts, out);
}

// Round 15
// 117.747 us; speedup vs baseline: 1.8542x; 1.0086x over previous
//
#include <hip/hip_runtime.h>
#include <math.h>

typedef unsigned short u16;
typedef __bf16 bf16x8 __attribute__((ext_vector_type(8)));
typedef float f32x4 __attribute__((ext_vector_type(4)));

#define T_TOKENS 4096   // B*S
#define D_DIM    512
#define H_DIM    2048
#define E_NUM    8
#define CAP      4096   // per-expert worst-case capacity
#define NSLOT    (T_TOKENS * 2)

__device__ __forceinline__ u16 f2bf(float f) {
  unsigned int u = __builtin_bit_cast(unsigned int, f);
  u = (u + 0x7fffu + ((u >> 16) & 1u)) >> 16;   // RNE
  return (u16)u;
}

__device__ __forceinline__ void gload16(const void* g, void* l) {
  __builtin_amdgcn_global_load_lds(
      (__attribute__((address_space(1))) void*)(g),
      (__attribute__((address_space(3))) void*)(l), 16, 0, 0);
}

// gelu(v) ~= v * sigmoid(v*(1.59576912 + 0.071354817*v^2)); rcp instead of slow f32 div
__device__ __forceinline__ float gelu_fast(float v) {
  float u = v * __fmaf_rn(0.071354817f, v * v, 1.59576912f);
  float e = __expf(-u);
  return v * __builtin_amdgcn_rcpf(1.0f + e);
}

// ---------------- merged prologue: weight transposes (blocks 0..4095) + router (4096..5119) ----
// transpose: f32 [E][R][C] -> bf16 [E][C][R]; router: logits, top-2, softmax, x->bf16, zero(out)
__global__ __launch_bounds__(256) void prologue_kernel(const float* __restrict__ w1,
                                                       const float* __restrict__ w2,
                                                       u16* __restrict__ w1t,
                                                       u16* __restrict__ w2t,
                                                       const float* __restrict__ x,
                                                       const float* __restrict__ rw,
                                                       const float* __restrict__ rb,
                                                       int* __restrict__ topk_idx,
                                                       float* __restrict__ topk_p,
                                                       u16* __restrict__ xb,
                                                       float* __restrict__ outz) {
  __shared__ float tile[64][67];
  const int tid = threadIdx.x;
  int bid = blockIdx.x;
  if (bid < 4096) {
    // ---- transpose path ----
    const float* in; u16* out; int R, C;
    if (bid < 2048) { in = w1; out = w1t; R = D_DIM; C = H_DIM; }
    else            { bid -= 2048; in = w2; out = w2t; R = H_DIM; C = D_DIM; }
    const int e = bid >> 8;
    const int t = bid & 255;
    const int nCx = C >> 6;
    const int c0 = (t % nCx) * 64, r0 = (t / nCx) * 64;
    const float* src = in + (size_t)e * D_DIM * H_DIM;
    u16* dst = out + (size_t)e * D_DIM * H_DIM;
    {
      const int row = tid >> 2, cc = (tid & 3) * 16;
      const float* s = src + (size_t)(r0 + row) * C + c0 + cc;
#pragma unroll
      for (int j = 0; j < 4; j++)
        *(float4*)(&tile[row][cc + 4 * j]) = *(const float4*)(s + 4 * j);
    }
    __syncthreads();
    {
      const int c = tid >> 2, rc = (tid & 3) * 16;
      u16 buf[16];
#pragma unroll
      for (int j = 0; j < 16; j++) buf[j] = f2bf(tile[rc + j][c]);
      u16* d = dst + (size_t)(c0 + c) * R + r0 + rc;
      *(uint4*)(d)     = *(uint4*)(&buf[0]);
      *(uint4*)(d + 8) = *(uint4*)(&buf[8]);
    }
    return;
  }
  // ---- router path ----
  const int rbid = bid - 4096;     // 0..1023
  {
    float4 z = {0.f, 0.f, 0.f, 0.f};
    float4* o = (float4*)(outz + (size_t)rbid * 2048);
    o[tid] = z;
    o[tid + 256] = z;
  }
  const int lane = tid & 63;
  const int t = rbid * 4 + (tid >> 6);
  const float* xr = x + (size_t)t * D_DIM + lane * 8;
  float xv[8];
  *(float4*)(&xv[0]) = *(const float4*)(xr);
  *(float4*)(&xv[4]) = *(const float4*)(xr + 4);
  ushort4 o0, o1;
  o0.x = f2bf(xv[0]); o0.y = f2bf(xv[1]); o0.z = f2bf(xv[2]); o0.w = f2bf(xv[3]);
  o1.x = f2bf(xv[4]); o1.y = f2bf(xv[5]); o1.z = f2bf(xv[6]); o1.w = f2bf(xv[7]);
  ushort4* xo = (ushort4*)(xb + (size_t)t * D_DIM + lane * 8);
  xo[0] = o0; xo[1] = o1;

  float acc[8] = {0.f,0.f,0.f,0.f,0.f,0.f,0.f,0.f};
#pragma unroll
  for (int j = 0; j < 8; j++) {
    const float4* w = (const float4*)(rw + (size_t)(lane * 8 + j) * E_NUM);
    float4 w0 = w[0], w1v = w[1];
    acc[0] += xv[j] * w0.x; acc[1] += xv[j] * w0.y;
    acc[2] += xv[j] * w0.z; acc[3] += xv[j] * w0.w;
    acc[4] += xv[j] * w1v.x; acc[5] += xv[j] * w1v.y;
    acc[6] += xv[j] * w1v.z; acc[7] += xv[j] * w1v.w;
  }
#pragma unroll
  for (int off = 32; off > 0; off >>= 1) {
#pragma unroll
    for (int e = 0; e < 8; e++) acc[e] += __shfl_down(acc[e], off);
  }
  if (lane == 0) {
    float l[8];
#pragma unroll
    for (int e = 0; e < 8; e++) l[e] = acc[e] + rb[e];
    int i0 = 0; float v0 = l[0];
#pragma unroll
    for (int e = 1; e < 8; e++) if (l[e] > v0) { v0 = l[e]; i0 = e; }
    int i1 = -1; float v1 = -3.4e38f;
#pragma unroll
    for (int e = 0; e < 8; e++) if (e != i0 && l[e] > v1) { v1 = l[e]; i1 = e; }
    float p1 = expf(v1 - v0);
    float s = 1.0f + p1;
    topk_idx[t * 2] = i0; topk_idx[t * 2 + 1] = i1;
    topk_p[t * 2] = 1.0f / s; topk_p[t * 2 + 1] = p1 / s;
  }
}

// ---------------- deterministic per-expert compaction (ballot scan, 8 blocks) ----------------
__global__ __launch_bounds__(256) void compact_kernel(const int* __restrict__ topk_idx,
                                                      const float* __restrict__ topk_p,
                                                      int* __restrict__ slot_list,
                                                      float* __restrict__ prob_list,
                                                      int* __restrict__ counts) {
  const int e = blockIdx.x;
  const int tid = threadIdx.x, lane = tid & 63, w = tid >> 6;
  __shared__ int wsum[4];
  __shared__ int sbase;
  if (tid == 0) sbase = 0;
  __syncthreads();
  for (int c0 = 0; c0 < T_TOKENS; c0 += 256) {
    const int t = c0 + tid;
    const int i0 = topk_idx[t * 2], i1 = topk_idx[t * 2 + 1];
    int flag = 0, slot = 0; float p = 0.f;
    if (i0 == e)      { flag = 1; slot = t * 2;     p = topk_p[t * 2]; }
    else if (i1 == e) { flag = 1; slot = t * 2 + 1; p = topk_p[t * 2 + 1]; }
    unsigned long long m = __ballot(flag);
    if (lane == 0) wsum[w] = (int)__popcll(m);
    const int wpre = (int)__popcll(m & ((1ull << lane) - 1ull));
    __syncthreads();
    int base = sbase;
#pragma unroll
    for (int j = 0; j < 4; j++) if (j < w) base += wsum[j];
    const int tot = wsum[0] + wsum[1] + wsum[2] + wsum[3];
    if (flag) { slot_list[e * CAP + base + wpre] = slot; prob_list[e * CAP + base + wpre] = p; }
    __syncthreads();
    if (tid == 0) sbase += tot;
  }
  __syncthreads();
  if (tid == 0) counts[e] = sbase;
}

// ---------------- grouped GEMM1: hc = gelu(x @ w1 + b1) * p (r7 loop + pin + compact) ----
// tile 64x128, BK=64, 2-buffer single-barrier loop, T2 swizzle, 48KB -> 3 blocks/CU
// flat grid 8192: e = bid&7 (XCD pin); g=bid>>3: cx = g&15, rt = g>>4 (0..63)
__global__ __launch_bounds__(256, 3) void gemm1_kernel(const u16* __restrict__ xb,
                                                       const u16* __restrict__ w1t,   // [E][H][D]
                                                       const float* __restrict__ b1,  // [E][H]
                                                       const int* __restrict__ slot_list,
                                                       const float* __restrict__ prob_list,
                                                       const int* __restrict__ counts,
                                                       u16* __restrict__ hbufc) {     // [NSLOT][H] compacted
  const int e  = blockIdx.x & 7;
  const int g  = blockIdx.x >> 3;
  const int cx = g & 15;
  const int rt = g >> 4;           // 0..63
  const int cnt = counts[e];
  const int rbase = rt * 64;
  if (rbase >= cnt) return;
  int ebase = 0;
#pragma unroll
  for (int j = 0; j < E_NUM; j++) if (j < e) ebase += counts[j];
  const int n0 = cx * 128;

  __shared__ __align__(16) u16 At[2][64 * 64];
  __shared__ __align__(16) u16 Bt[2][128 * 64];

  const int tid = threadIdx.x, lane = tid & 63, wid = tid >> 6;
  const int wr = wid >> 1, wc = wid & 1;
  const int lr8 = lane >> 3;
  const int sx = lane & 7;
  const int kperm = (sx ^ lr8) * 8;
  const int lrow = lane & 15, lk = lane >> 4;

  const u16* pa[2]; int loa[2];
#pragma unroll
  for (int i = 0; i < 2; i++) {
    const int row = (wid * 2 + i) * 8 + lr8;          // 0..63
    const int grow = rbase + row;
    int tok = 0;
    if (grow < cnt) tok = slot_list[e * CAP + grow] >> 1;
    pa[i] = xb + (size_t)tok * D_DIM + kperm;
    loa[i] = (wid * 2 + i) * 512;
  }
  const u16* pb[4]; int lob[4];
#pragma unroll
  for (int i = 0; i < 4; i++) {
    const int row = (wid * 4 + i) * 8 + lr8;          // 0..127
    pb[i] = w1t + ((size_t)e * H_DIM + n0 + row) * D_DIM + kperm;
    lob[i] = (wid * 4 + i) * 512;
  }

  f32x4 acc[2][4];
#pragma unroll
  for (int i = 0; i < 2; i++)
#pragma unroll
    for (int j = 0; j < 4; j++) acc[i][j] = (f32x4){0.f, 0.f, 0.f, 0.f};

  auto stage = [&](int k0, int b) {   // 6 gload_lds per thread
#pragma unroll
    for (int i = 0; i < 2; i++) gload16(pa[i] + k0, &At[b][loa[i]]);
#pragma unroll
    for (int i = 0; i < 4; i++) gload16(pb[i] + k0, &Bt[b][lob[i]]);
  };

  stage(0, 0);
  const int nt = D_DIM / 64;   // 8
  int cur = 0;
  for (int t = 0; t < nt; ++t) {
    asm volatile("s_waitcnt vmcnt(0)" ::: "memory");   // stage(t) resident (issued last step)
    __builtin_amdgcn_sched_barrier(0);
    __builtin_amdgcn_s_barrier();                      // all waves: buf[cur] ready, buf[cur^1] free
    if (t + 1 < nt) stage((t + 1) * 64, cur ^ 1);      // issue early; hides under ds_read+MFMA
    bf16x8 afr[2][2], bfr[4][2];
#pragma unroll
    for (int ks = 0; ks < 2; ks++) {
#pragma unroll
      for (int fq = 0; fq < 2; fq++)
        afr[fq][ks] = *(const bf16x8*)(&At[cur][(wr * 32 + fq * 16 + lrow) * 64 + ((ks * 4 + lk) ^ sx) * 8]);
#pragma unroll
      for (int fq = 0; fq < 4; fq++)
        bfr[fq][ks] = *(const bf16x8*)(&Bt[cur][(wc * 64 + fq * 16 + lrow) * 64 + ((ks * 4 + lk) ^ sx) * 8]);
    }
    asm volatile("s_waitcnt lgkmcnt(0)" ::: "memory"); // reads of buf[cur] drained before next barrier
    __builtin_amdgcn_sched_barrier(0);
    __builtin_amdgcn_s_setprio(1);
#pragma unroll
    for (int ks = 0; ks < 2; ks++)
#pragma unroll
      for (int fr = 0; fr < 2; fr++)
#pragma unroll
        for (int fc = 0; fc < 4; fc++)
          acc[fr][fc] = __builtin_amdgcn_mfma_f32_16x16x32_bf16(afr[fr][ks], bfr[fc][ks], acc[fr][fc], 0, 0, 0);
    __builtin_amdgcn_s_setprio(0);
    cur ^= 1;
  }

  float bias[4];
#pragma unroll
  for (int fc = 0; fc < 4; fc++) bias[fc] = b1[e * H_DIM + n0 + wc * 64 + fc * 16 + lrow];
#pragma unroll
  for (int fr = 0; fr < 2; fr++) {
#pragma unroll
    for (int reg = 0; reg < 4; reg++) {
      const int rloc = wr * 32 + fr * 16 + lk * 4 + reg;
      const int grow = rbase + rloc;
      if (grow < cnt) {
        const float p = prob_list[e * CAP + grow];
        u16* dst = hbufc + (size_t)(ebase + grow) * H_DIM + n0 + wc * 64 + lrow;
#pragma unroll
        for (int fc = 0; fc < 4; fc++) {
          float v = acc[fr][fc][reg] + bias[fc];
          dst[fc * 16] = f2bf(gelu_fast(v) * p);
        }
      }
    }
  }
}

// ---------------- grouped GEMM2: out[t] += hc @ w2 + p*b2 (atomic f32, 2 addends) -------
// tile 64x128, BK=64, single-barrier dbuf (r7 best), compacted A, XCD pin, 48KB -> 3/CU
// flat grid 2048: e = bid&7; g=bid>>3: cx = g&3, rt = g>>2 (0..63)
__global__ __launch_bounds__(256, 3) void gemm2_kernel(const u16* __restrict__ hbufc, // [NSLOT][H] compacted
                                                       const u16* __restrict__ w2t,   // [E][D][H]
                                                       const float* __restrict__ b2,  // [E][D]
                                                       const int* __restrict__ slot_list,
                                                       const float* __restrict__ prob_list,
                                                       const int* __restrict__ counts,
                                                       float* __restrict__ out) {     // [T][D]
  const int e  = blockIdx.x & 7;
  const int g  = blockIdx.x >> 3;
  const int cx = g & 3;
  const int rt = g >> 2;           // 0..63
  const int cnt = counts[e];
  const int rbase = rt * 64;
  if (rbase >= cnt) return;
  int ebase = 0;
#pragma unroll
  for (int j = 0; j < E_NUM; j++) if (j < e) ebase += counts[j];
  const int n0 = cx * 128;

  __shared__ __align__(16) u16 At[2][64 * 64];
  __shared__ __align__(16) u16 Bt[2][128 * 64];

  const int tid = threadIdx.x, lane = tid & 63, wid = tid >> 6;
  const int wr = wid >> 1, wc = wid & 1;
  const int lr8 = lane >> 3;
  const int sx = lane & 7;
  const int kperm = (sx ^ lr8) * 8;
  const int lrow = lane & 15, lk = lane >> 4;

  const u16* pa[2]; int loa[2];
#pragma unroll
  for (int i = 0; i < 2; i++) {
    const int row = (wid * 2 + i) * 8 + lr8;          // 0..63
    const int grow = rbase + row;
    const int cr = (grow < cnt) ? (ebase + grow) : 0; // compacted, contiguous per expert
    pa[i] = hbufc + (size_t)cr * H_DIM + kperm;
    loa[i] = (wid * 2 + i) * 512;
  }
  const u16* pb[4]; int lob[4];
#pragma unroll
  for (int i = 0; i < 4; i++) {
    const int row = (wid * 4 + i) * 8 + lr8;          // 0..127
    pb[i] = w2t + ((size_t)e * D_DIM + n0 + row) * H_DIM + kperm;
    lob[i] = (wid * 4 + i) * 512;
  }

  f32x4 acc[2][4];
#pragma unroll
  for (int i = 0; i < 2; i++)
#pragma unroll
    for (int j = 0; j < 4; j++) acc[i][j] = (f32x4){0.f, 0.f, 0.f, 0.f};

  auto stage = [&](int k0, int b) {   // 6 gload_lds per thread
#pragma unroll
    for (int i = 0; i < 2; i++) gload16(pa[i] + k0, &At[b][loa[i]]);
#pragma unroll
    for (int i = 0; i < 4; i++) gload16(pb[i] + k0, &Bt[b][lob[i]]);
  };

  stage(0, 0);
  const int nt = H_DIM / 64;   // 32
  int cur = 0;
  for (int t = 0; t < nt; ++t) {
    asm volatile("s_waitcnt vmcnt(0)" ::: "memory");
    __builtin_amdgcn_sched_barrier(0);
    __builtin_amdgcn_s_barrier();
    if (t + 1 < nt) stage((t + 1) * 64, cur ^ 1);
    bf16x8 afr[2][2], bfr[4][2];
#pragma unroll
    for (int ks = 0; ks < 2; ks++) {
#pragma unroll
      for (int fq = 0; fq < 2; fq++)
        afr[fq][ks] = *(const bf16x8*)(&At[cur][(wr * 32 + fq * 16 + lrow) * 64 + ((ks * 4 + lk) ^ sx) * 8]);
#pragma unroll
      for (int fq = 0; fq < 4; fq++)
        bfr[fq][ks] = *(const bf16x8*)(&Bt[cur][(wc * 64 + fq * 16 + lrow) * 64 + ((ks * 4 + lk) ^ sx) * 8]);
    }
    asm volatile("s_waitcnt lgkmcnt(0)" ::: "memory");
    __builtin_amdgcn_sched_barrier(0);
    __builtin_amdgcn_s_setprio(1);
#pragma unroll
    for (int ks = 0; ks < 2; ks++)
#pragma unroll
      for (int fr = 0; fr < 2; fr++)
#pragma unroll
        for (int fc = 0; fc < 4; fc++)
          acc[fr][fc] = __builtin_amdgcn_mfma_f32_16x16x32_bf16(afr[fr][ks], bfr[fc][ks], acc[fr][fc], 0, 0, 0);
    __builtin_amdgcn_s_setprio(0);
    cur ^= 1;
  }

  // epilogue: out[token] += acc + p*b2 (exactly 2 atomic addends per element -> deterministic)
#pragma unroll
  for (int fr = 0; fr < 2; fr++) {
#pragma unroll
    for (int reg = 0; reg < 4; reg++) {
      const int rloc = wr * 32 + fr * 16 + lk * 4 + reg;
      const int grow = rbase + rloc;
      if (grow < cnt) {
        const int slot = slot_list[e * CAP + grow];
        const float p  = prob_list[e * CAP + grow];
        float* dst = out + (size_t)(slot >> 1) * D_DIM + n0 + wc * 64 + lrow;
#pragma unroll
        for (int fc = 0; fc < 4; fc++) {
          float v = acc[fr][fc][reg] + p * b2[e * D_DIM + n0 + wc * 64 + fc * 16 + lrow];
          atomicAdd(&dst[fc * 16], v);
        }
      }
    }
  }
}

extern "C" void kernel_launch(void* const* d_in, const int* in_sizes, int n_in,
                              void* d_out, int out_size, void* d_ws, size_t ws_size,
                              hipStream_t stream) {
  const float* x  = (const float*)d_in[0];
  const float* w1 = (const float*)d_in[1];
  const float* w2 = (const float*)d_in[2];
  const float* b1 = (const float*)d_in[3];
  const float* b2 = (const float*)d_in[4];
  const float* rw = (const float*)d_in[5];
  const float* rb = (const float*)d_in[6];
  float* out = (float*)d_out;

  char* ws = (char*)d_ws;
  size_t off = 0;
  auto alloc = [&](size_t bytes) -> void* {
    void* p = ws + off;
    off = (off + bytes + 255) & ~(size_t)255;
    return p;
  };
  int*   counts    = (int*)alloc(E_NUM * 4);
  int*   slot_list = (int*)alloc((size_t)E_NUM * CAP * 4);
  float* prob_list = (float*)alloc((size_t)E_NUM * CAP * 4);
  int*   topk_idx  = (int*)alloc((size_t)T_TOKENS * 2 * 4);
  float* topk_p    = (float*)alloc((size_t)T_TOKENS * 2 * 4);
  u16*   xb        = (u16*)alloc((size_t)T_TOKENS * D_DIM * 2);
  u16*   w1t       = (u16*)alloc((size_t)E_NUM * H_DIM * D_DIM * 2);
  u16*   w2t       = (u16*)alloc((size_t)E_NUM * H_DIM * D_DIM * 2);
  u16*   hbufc     = (u16*)alloc((size_t)NSLOT * H_DIM * 2);

  prologue_kernel<<<4096 + T_TOKENS / 4, 256, 0, stream>>>(w1, w2, w1t, w2t,
                                                           x, rw, rb, topk_idx, topk_p, xb, out);
  compact_kernel<<<E_NUM, 256, 0, stream>>>(topk_idx, topk_p, slot_list, prob_list, counts);
  gemm1_kernel<<<E_NUM * 16 * 64, 256, 0, stream>>>(xb, w1t, b1, slot_list, prob_list, counts, hbufc);
  gemm2_kernel<<<E_NUM * 4 * 64, 256, 0, stream>>>(hbufc, w2t, b2, slot_list, prob_list, counts, out);
}